// Round 9
// baseline (32.005 us; speedup 1.0000x reference)
//
#include <hip/hip_runtime.h>

#define S_TOT 2048
#define B_SZ  32
#define I_SZ  256
#define O_SZ  80

typedef _Float16 f16x8 __attribute__((ext_vector_type(8)));
typedef float    f32x4 __attribute__((ext_vector_type(4)));

// Round-7 structure re-shaped to 4-wave / 256-thread blocks so that
// launch_bounds(256,8) gives 8 blocks/CU -> ALL 2048 blocks resident at
// t=0 (LDS 8x16KB=128<=160KB, 32 waves/CU exactly). Removes the dispatch
// quantization of 5-wave blocks (6/CU, 1536 resident, late blocks start
// their loads late -> starved tail). Wave w owns o-chunk w (o=16w..16w+16).
// Chunk 4 (o 64..79) is active only when out_sz>64 (~18% of s): wave 3
// runs it as a second pass after its primary epilogue (disjoint register
// liveness -> no VGPR growth); otherwise wave 3 writes its zeros.
// LDS: X only (32x256 f16, 16KB, XOR-swizzle byte ^= (row&7)<<4 ->
// conflict-free ds_read_b128). W: global->reg (no inter-wave reuse),
// round-7 load pattern (round-8 batching reverted: hurt occupancy).
// RAGGED-K: skip K-chunks >= kcmax (in_mask prefix-ones), exact.
// RAGGED-O: masked waves store zeros; masked lanes skip W loads, exact.
__device__ __forceinline__ float ftanh(float v) {
  float e = __expf(2.0f * v);
  return 1.0f - __fdividef(2.0f, e + 1.0f);
}

__device__ __forceinline__ f16x8 cvt8(f32x4 lo, f32x4 hi) {
  f16x8 h;
  h[0] = (_Float16)lo[0]; h[1] = (_Float16)lo[1];
  h[2] = (_Float16)lo[2]; h[3] = (_Float16)lo[3];
  h[4] = (_Float16)hi[0]; h[5] = (_Float16)hi[1];
  h[6] = (_Float16)hi[2]; h[7] = (_Float16)hi[3];
  return h;
}

__global__ __launch_bounds__(256, 8) void dcell_kernel(
    const float* __restrict__ x,        // [S, 32, 256]
    const float* __restrict__ W,        // [S, 80, 256]
    const float* __restrict__ bias,     // [S, 80]
    const float* __restrict__ gamma,    // [S, 80]
    const float* __restrict__ beta,     // [S, 80]
    const float* __restrict__ in_mask,  // [S, 256]
    const float* __restrict__ out_mask, // [S, 80]
    float* __restrict__ out)            // [S, 32, 80]
{
  __shared__ char Xs[16384];  // 32 rows * 512B

  const int s   = blockIdx.x;
  const int tid = threadIdx.x;

  const int w  = tid >> 6;   // wave 0..3 -> primary o-chunk
  const int l  = tid & 63;
  const int m  = l & 15;     // A row / B col within tile
  const int ks = l >> 4;     // k-slice 0..3
  const int ob = w * 16;
  const int o  = ob + m;
  const int swz = (m & 7) << 4;

  // ---- active K-chunk count (block-uniform; in_mask is prefix-ones)
  const float* im = in_mask + (size_t)s * I_SZ;
  float msum = im[0] + im[32] + im[64] + im[96] +
               im[128] + im[160] + im[192] + im[224];
  const int kcmax = (int)(msum + 0.5f);   // 1..8
  const int Kact  = kcmax * 32;

  const float* omp = out_mask + (size_t)s * O_SZ;
  const bool wave_act = (omp[ob] != 0.0f);   // prefix-ones
  const bool lane_act = (omp[o]  != 0.0f);

  // hoist epilogue scalars so their latency hides under staging
  const float bv  = bias[s * O_SZ + o];
  const float gm  = gamma[s * O_SZ + o];
  const float be  = beta[s * O_SZ + o];
  const float om  = omp[o];

  // ---- stage X: f32 -> f16, swizzled; 1024 x 32B chunks = exactly 4
  // unrolled iters/thread. chunk t: row r = t>>5, cols c = (t&31)*8..+8
  // (Kact multiple of 32 -> whole chunk on one side of the guard).
  {
    const float* xg = x + (size_t)s * (B_SZ * I_SZ);
#pragma unroll
    for (int i = 0; i < 4; ++i) {
      int t = tid + i * 256;
      int r = t >> 5, c = (t & 31) * 8;
      if (c < Kact) {
        f32x4 lo = *(const f32x4*)(xg + t * 8);
        f32x4 hi = *(const f32x4*)(xg + t * 8 + 4);
        int off = r * 512 + ((c * 2) ^ ((r & 7) << 4));
        *(f16x8*)(Xs + off) = cvt8(lo, hi);
      }
    }
  }

  // ---- W fragments (primary chunk): global -> reg, f32 -> f16; active
  // chunks AND active o-rows only. Lane (m,ks) holds W[o][kc*32+ks*8..+8).
  f16x8 wf[8];
  {
    const float* wgp = W + ((size_t)s * O_SZ + o) * I_SZ + ks * 8;
#pragma unroll
    for (int kc = 0; kc < 8; ++kc) {
      if (kc < kcmax) {
        f16x8 h = {0, 0, 0, 0, 0, 0, 0, 0};
        if (lane_act) {
          f32x4 lo = *(const f32x4*)(wgp + kc * 32);
          f32x4 hi = *(const f32x4*)(wgp + kc * 32 + 4);
          h = cvt8(lo, hi);
        }
        wf[kc] = h;
      }
    }
  }
  __syncthreads();

  const char* xr0 = Xs + m * 512;
  const char* xr1 = Xs + (m + 16) * 512;   // (m+16)&7 == m&7
  float* og = out + (size_t)s * (B_SZ * O_SZ) + o;

  // ================= pass 1: primary chunk =================
  if (wave_act) {
    f32x4 acc0 = {0.f, 0.f, 0.f, 0.f};
    f32x4 acc1 = {0.f, 0.f, 0.f, 0.f};
#pragma unroll
    for (int kc = 0; kc < 8; ++kc) {
      if (kc < kcmax) {
        int kb = (kc * 64 + ks * 16) ^ swz;
        f16x8 a0 = *(const f16x8*)(xr0 + kb);
        f16x8 a1 = *(const f16x8*)(xr1 + kb);
        acc0 = __builtin_amdgcn_mfma_f32_16x16x32_f16(a0, wf[kc], acc0, 0, 0, 0);
        acc1 = __builtin_amdgcn_mfma_f32_16x16x32_f16(a1, wf[kc], acc1, 0, 0, 0);
      }
    }
    // epilogue: bias, tanh, BN over b (in-register), mask, store.
    // C layout (m89): col = lane&15, row = (lane>>4)*4 + reg.
    float t0[4], t1[4];
    float sum = 0.f;
#pragma unroll
    for (int r = 0; r < 4; ++r) {
      t0[r] = ftanh(acc0[r] + bv);
      t1[r] = ftanh(acc1[r] + bv);
      sum += t0[r] + t1[r];
    }
    sum += __shfl_xor(sum, 16);
    sum += __shfl_xor(sum, 32);
    const float mean = sum * (1.0f / 32.0f);

    float vs = 0.f;
#pragma unroll
    for (int r = 0; r < 4; ++r) {
      float d0 = t0[r] - mean, d1 = t1[r] - mean;
      vs += d0 * d0 + d1 * d1;
    }
    vs += __shfl_xor(vs, 16);
    vs += __shfl_xor(vs, 32);
    const float rstd = rsqrtf(vs * (1.0f / 32.0f) + 1e-5f);
    const float g = gm * rstd;
#pragma unroll
    for (int r = 0; r < 4; ++r) {
      int b0 = ks * 4 + r;
      og[(size_t)b0 * O_SZ]        = ((t0[r] - mean) * g + be) * om;
      og[(size_t)(b0 + 16) * O_SZ] = ((t1[r] - mean) * g + be) * om;
    }
  } else {
#pragma unroll
    for (int r = 0; r < 4; ++r) {
      int b0 = ks * 4 + r;
      og[(size_t)b0 * O_SZ]        = 0.f;
      og[(size_t)(b0 + 16) * O_SZ] = 0.f;
    }
  }

  // ================= pass 2: chunk 4 (o 64..79), wave 3 only =============
  if (w == 3) {
    const int o2 = 64 + m;
    float* og2 = out + (size_t)s * (B_SZ * O_SZ) + o2;
    if (omp[64] != 0.0f) {             // out_sz > 64: ~18% of subsystems
      const bool lane2 = (omp[o2] != 0.0f);
      f16x8 wf2[8];
      {
        const float* wgp2 = W + ((size_t)s * O_SZ + o2) * I_SZ + ks * 8;
#pragma unroll
        for (int kc = 0; kc < 8; ++kc) {
          if (kc < kcmax) {
            f16x8 h = {0, 0, 0, 0, 0, 0, 0, 0};
            if (lane2) {
              f32x4 lo = *(const f32x4*)(wgp2 + kc * 32);
              f32x4 hi = *(const f32x4*)(wgp2 + kc * 32 + 4);
              h = cvt8(lo, hi);
            }
            wf2[kc] = h;
          }
        }
      }
      f32x4 acc0 = {0.f, 0.f, 0.f, 0.f};
      f32x4 acc1 = {0.f, 0.f, 0.f, 0.f};
#pragma unroll
      for (int kc = 0; kc < 8; ++kc) {
        if (kc < kcmax) {
          int kb = (kc * 64 + ks * 16) ^ swz;
          f16x8 a0 = *(const f16x8*)(xr0 + kb);
          f16x8 a1 = *(const f16x8*)(xr1 + kb);
          acc0 = __builtin_amdgcn_mfma_f32_16x16x32_f16(a0, wf2[kc], acc0, 0, 0, 0);
          acc1 = __builtin_amdgcn_mfma_f32_16x16x32_f16(a1, wf2[kc], acc1, 0, 0, 0);
        }
      }
      const float bv2 = bias[s * O_SZ + o2];
      float t0[4], t1[4];
      float sum = 0.f;
#pragma unroll
      for (int r = 0; r < 4; ++r) {
        t0[r] = ftanh(acc0[r] + bv2);
        t1[r] = ftanh(acc1[r] + bv2);
        sum += t0[r] + t1[r];
      }
      sum += __shfl_xor(sum, 16);
      sum += __shfl_xor(sum, 32);
      const float mean = sum * (1.0f / 32.0f);

      float vs = 0.f;
#pragma unroll
      for (int r = 0; r < 4; ++r) {
        float d0 = t0[r] - mean, d1 = t1[r] - mean;
        vs += d0 * d0 + d1 * d1;
      }
      vs += __shfl_xor(vs, 16);
      vs += __shfl_xor(vs, 32);
      const float rstd = rsqrtf(vs * (1.0f / 32.0f) + 1e-5f);
      const float g2  = gamma[s * O_SZ + o2] * rstd;
      const float be2 = beta[s * O_SZ + o2];
      const float om2 = omp[o2];
#pragma unroll
      for (int r = 0; r < 4; ++r) {
        int b0 = ks * 4 + r;
        og2[(size_t)b0 * O_SZ]        = ((t0[r] - mean) * g2 + be2) * om2;
        og2[(size_t)(b0 + 16) * O_SZ] = ((t1[r] - mean) * g2 + be2) * om2;
      }
    } else {
#pragma unroll
      for (int r = 0; r < 4; ++r) {
        int b0 = ks * 4 + r;
        og2[(size_t)b0 * O_SZ]        = 0.f;
        og2[(size_t)(b0 + 16) * O_SZ] = 0.f;
      }
    }
  }
}

extern "C" void kernel_launch(void* const* d_in, const int* in_sizes, int n_in,
                              void* d_out, int out_size, void* d_ws, size_t ws_size,
                              hipStream_t stream) {
  const float* x        = (const float*)d_in[0];
  const float* W        = (const float*)d_in[1];
  const float* bias     = (const float*)d_in[2];
  const float* gamma    = (const float*)d_in[3];
  const float* beta     = (const float*)d_in[4];
  const float* in_mask  = (const float*)d_in[5];
  const float* out_mask = (const float*)d_in[6];
  float* out = (float*)d_out;

  dcell_kernel<<<dim3(S_TOT), dim3(256), 0, stream>>>(
      x, W, bias, gamma, beta, in_mask, out_mask, out);
}

// Round 10
// 28.644 us; speedup vs baseline: 1.1173x; 1.1173x over previous
//
#include <hip/hip_runtime.h>

#define S_TOT 2048
#define B_SZ  32
#define I_SZ  256
#define O_SZ  80

typedef _Float16 f16x8 __attribute__((ext_vector_type(8)));
typedef float    f32x4 __attribute__((ext_vector_type(4)));

// FINAL (round-7 configuration, best measured: 28.7 us).
// Static grid, 1 block = 1 subsystem, 5 waves (320t); wave w owns o-chunk
// [16w,16w+16). LDS = X only (32x256 f16, 16KB, XOR-swizzle
// byte ^= (row&7)<<4 -> conflict-free ds_read_b128 fragments). W has no
// inter-wave reuse -> global->reg fragments with the SAME (lane,ks)->k map
// as the A-side LDS reads. f16 MFMA (16x16x32): compute is negligible;
// kernel is memory/latency-bound at ~4.4 TB/s effective.
// RAGGED-K: x is pre-masked beyond in_size -> K-chunks >= kcmax contribute
//   exactly 0 -> skip their x reads, W reads, MFMAs (kcmax from in_mask
//   prefix-ones, block-uniform). Exact.
// RAGGED-O: *out_mask zeroes o >= out_sz and BN is per-(s,o) -> W rows for
//   masked o are irrelevant. Fully-masked waves store zeros; masked lanes
//   skip W loads (wf zeroed -> NaN-free, om=0 path exact).
// Falsified alternatives (rounds 5-9): no-LDS per-wave global A-fragments
// (-38%), persistent+ticket (-100%), forced W-load MLP @ lower occupancy
// (-6%), 4-wave full-residency blocks (-11%).
__device__ __forceinline__ float ftanh(float v) {
  float e = __expf(2.0f * v);
  return 1.0f - __fdividef(2.0f, e + 1.0f);
}

__device__ __forceinline__ f16x8 cvt8(f32x4 lo, f32x4 hi) {
  f16x8 h;
  h[0] = (_Float16)lo[0]; h[1] = (_Float16)lo[1];
  h[2] = (_Float16)lo[2]; h[3] = (_Float16)lo[3];
  h[4] = (_Float16)hi[0]; h[5] = (_Float16)hi[1];
  h[6] = (_Float16)hi[2]; h[7] = (_Float16)hi[3];
  return h;
}

__global__ __launch_bounds__(320, 8) void dcell_kernel(
    const float* __restrict__ x,        // [S, 32, 256]
    const float* __restrict__ W,        // [S, 80, 256]
    const float* __restrict__ bias,     // [S, 80]
    const float* __restrict__ gamma,    // [S, 80]
    const float* __restrict__ beta,     // [S, 80]
    const float* __restrict__ in_mask,  // [S, 256]
    const float* __restrict__ out_mask, // [S, 80]
    float* __restrict__ out)            // [S, 32, 80]
{
  __shared__ char Xs[16384];  // 32 rows * 512B

  const int s   = blockIdx.x;
  const int tid = threadIdx.x;

  const int w  = tid >> 6;   // wave 0..4 -> o-chunk
  const int l  = tid & 63;
  const int m  = l & 15;     // A row / B col within tile
  const int ks = l >> 4;     // k-slice 0..3
  const int ob = w * 16;
  const int o  = ob + m;
  const int swz = (m & 7) << 4;

  // ---- active K-chunk count (block-uniform; in_mask is prefix-ones)
  const float* im = in_mask + (size_t)s * I_SZ;
  float msum = im[0] + im[32] + im[64] + im[96] +
               im[128] + im[160] + im[192] + im[224];
  const int kcmax = (int)(msum + 0.5f);   // 1..8
  const int Kact  = kcmax * 32;

  const float* omp = out_mask + (size_t)s * O_SZ;
  const bool wave_act = (omp[ob] != 0.0f);   // prefix-ones
  const bool lane_act = (omp[o]  != 0.0f);

  // hoist epilogue scalars so their latency hides under staging
  const float bv  = bias[s * O_SZ + o];
  const float gm  = gamma[s * O_SZ + o];
  const float be  = beta[s * O_SZ + o];
  const float om  = omp[o];

  // ---- stage X: f32 -> f16, swizzled; 1024 x 32B chunks, unrolled.
  // chunk t: row r = t>>5, cols c = (t&31)*8 .. +8 (Kact multiple of 32
  // -> both halves of a chunk are on the same side of the guard).
  {
    const float* xg = x + (size_t)s * (B_SZ * I_SZ);
#pragma unroll
    for (int i = 0; i < 3; ++i) {
      int t = tid + i * 320;
      int r = t >> 5, c = (t & 31) * 8;
      if (c < Kact) {
        f32x4 lo = *(const f32x4*)(xg + t * 8);
        f32x4 hi = *(const f32x4*)(xg + t * 8 + 4);
        int off = r * 512 + ((c * 2) ^ ((r & 7) << 4));
        *(f16x8*)(Xs + off) = cvt8(lo, hi);
      }
    }
    if (tid < 64) {
      int t = 960 + tid;
      int r = t >> 5, c = (t & 31) * 8;
      if (c < Kact) {
        f32x4 lo = *(const f32x4*)(xg + t * 8);
        f32x4 hi = *(const f32x4*)(xg + t * 8 + 4);
        int off = r * 512 + ((c * 2) ^ ((r & 7) << 4));
        *(f16x8*)(Xs + off) = cvt8(lo, hi);
      }
    }
  }

  // ---- W fragments: global -> reg, f32 -> f16; active chunks AND active
  // o-rows only. Lane (m,ks) of wave w holds W[o][kc*32 + ks*8 .. +8).
  f16x8 wf[8];
  {
    const float* wgp = W + ((size_t)s * O_SZ + o) * I_SZ + ks * 8;
#pragma unroll
    for (int kc = 0; kc < 8; ++kc) {
      if (kc < kcmax) {
        f16x8 h = {0, 0, 0, 0, 0, 0, 0, 0};
        if (lane_act) {
          f32x4 lo = *(const f32x4*)(wgp + kc * 32);
          f32x4 hi = *(const f32x4*)(wgp + kc * 32 + 4);
          h = cvt8(lo, hi);
        }
        wf[kc] = h;
      }
    }
  }
  __syncthreads();

  float* og = out + (size_t)s * (B_SZ * O_SZ) + o;

  if (wave_act) {
    // ---- per-wave GEMM: two 16x16 tiles (b=0..15, b=16..31), K=Kact
    f32x4 acc0 = {0.f, 0.f, 0.f, 0.f};
    f32x4 acc1 = {0.f, 0.f, 0.f, 0.f};
    const char* xr0 = Xs + m * 512;
    const char* xr1 = Xs + (m + 16) * 512;   // (m+16)&7 == m&7
#pragma unroll
    for (int kc = 0; kc < 8; ++kc) {
      if (kc < kcmax) {
        int kb = (kc * 64 + ks * 16) ^ swz;
        f16x8 a0 = *(const f16x8*)(xr0 + kb);
        f16x8 a1 = *(const f16x8*)(xr1 + kb);
        acc0 = __builtin_amdgcn_mfma_f32_16x16x32_f16(a0, wf[kc], acc0, 0, 0, 0);
        acc1 = __builtin_amdgcn_mfma_f32_16x16x32_f16(a1, wf[kc], acc1, 0, 0, 0);
      }
    }

    // ---- epilogue: bias, tanh, BN over b (in-register), mask, store.
    // C layout (m89): col = lane&15, row = (lane>>4)*4 + reg.
    float t0[4], t1[4];
    float sum = 0.f;
#pragma unroll
    for (int r = 0; r < 4; ++r) {
      t0[r] = ftanh(acc0[r] + bv);
      t1[r] = ftanh(acc1[r] + bv);
      sum += t0[r] + t1[r];
    }
    sum += __shfl_xor(sum, 16);
    sum += __shfl_xor(sum, 32);
    const float mean = sum * (1.0f / 32.0f);

    float vs = 0.f;
#pragma unroll
    for (int r = 0; r < 4; ++r) {
      float d0 = t0[r] - mean, d1 = t1[r] - mean;
      vs += d0 * d0 + d1 * d1;
    }
    vs += __shfl_xor(vs, 16);
    vs += __shfl_xor(vs, 32);
    const float rstd = rsqrtf(vs * (1.0f / 32.0f) + 1e-5f);

    const float g = gm * rstd;

#pragma unroll
    for (int r = 0; r < 4; ++r) {
      int b0 = ks * 4 + r;
      og[(size_t)b0 * O_SZ]        = ((t0[r] - mean) * g + be) * om;
      og[(size_t)(b0 + 16) * O_SZ] = ((t1[r] - mean) * g + be) * om;
    }
  } else {
    // fully-masked o-chunk: output exactly 0 (d_out is poisoned).
#pragma unroll
    for (int r = 0; r < 4; ++r) {
      int b0 = ks * 4 + r;
      og[(size_t)b0 * O_SZ]        = 0.f;
      og[(size_t)(b0 + 16) * O_SZ] = 0.f;
    }
  }
}

extern "C" void kernel_launch(void* const* d_in, const int* in_sizes, int n_in,
                              void* d_out, int out_size, void* d_ws, size_t ws_size,
                              hipStream_t stream) {
  const float* x        = (const float*)d_in[0];
  const float* W        = (const float*)d_in[1];
  const float* bias     = (const float*)d_in[2];
  const float* gamma    = (const float*)d_in[3];
  const float* beta     = (const float*)d_in[4];
  const float* in_mask  = (const float*)d_in[5];
  const float* out_mask = (const float*)d_in[6];
  float* out = (float*)d_out;

  dcell_kernel<<<dim3(S_TOT), dim3(320), 0, stream>>>(
      x, W, bias, gamma, beta, in_mask, out_mask, out);
}